// Round 1
// baseline (1102.174 us; speedup 1.0000x reference)
//
#include <hip/hip_runtime.h>
#include <hip/hip_bf16.h>
#include <stdint.h>

// GraphUnet forward, N=4096 nodes, D=128, E=131072 edges, K=2457 kept.
// All inputs/outputs float32. Strategy: bitset 2-hop, exact-rank top-k
// (order-invariant), sparse edge propagation. No dense NxN matrices.

#define NN 4096
#define DD 128
#define KKEEP 2457              // int(0.6*4096)
#define SUBW 40                 // ceil(KKEEP/64)

typedef unsigned long long u64;

__global__ void k_build_bits(const int* __restrict__ g, int E,
                             u64* __restrict__ rowbits, u64* __restrict__ colbits) {
    int e = blockIdx.x * 256 + threadIdx.x;
    if (e >= E) return;
    int s = g[e], d2 = g[E + e];
    atomicOr(&rowbits[(size_t)s * 64 + (d2 >> 6)], 1ull << (d2 & 63));
    atomicOr(&colbits[(size_t)d2 * 64 + (s >> 6)], 1ull << (s & 63));
}

// h0 = h @ Wd + bd
__global__ void k_h0(const float* __restrict__ h, const float* __restrict__ Wd,
                     const float* __restrict__ bd, float* __restrict__ h0) {
    __shared__ float row[DD];
    int r = blockIdx.x, d = threadIdx.x;
    row[d] = h[(size_t)r * DD + d];
    __syncthreads();
    float acc = bd[d];
    #pragma unroll 4
    for (int k = 0; k < DD; ++k) acc += row[k] * Wd[k * DD + d];
    h0[(size_t)r * DD + d] = acc;
}

// scores = sigmoid(h0 @ pw + pb)
__global__ void k_score(const float* __restrict__ h0, const float* __restrict__ pw,
                        const float* __restrict__ pb, float* __restrict__ scores) {
    __shared__ float red[DD];
    int r = blockIdx.x, tid = threadIdx.x;
    red[tid] = h0[(size_t)r * DD + tid] * pw[tid];
    __syncthreads();
    for (int sft = 64; sft > 0; sft >>= 1) {
        if (tid < sft) red[tid] += red[tid + sft];
        __syncthreads();
    }
    if (tid == 0) scores[r] = 1.0f / (1.0f + expf(-(red[0] + pb[0])));
}

// Exact top-k rank (matches jax.lax.top_k: score desc, index asc on ties).
__global__ void k_rank(const float* __restrict__ scores, int* __restrict__ keep,
                       int* __restrict__ pos, int* __restrict__ idxl) {
    __shared__ float chunk[256];
    int i = blockIdx.x * 256 + threadIdx.x;
    float my = scores[i];
    int rank = 0;
    for (int base = 0; base < NN; base += 256) {
        chunk[threadIdx.x] = scores[base + threadIdx.x];
        __syncthreads();
        for (int j = 0; j < 256; ++j) {
            float sj = chunk[j];
            int jj = base + j;
            rank += ((sj > my) || (sj == my && jj < i)) ? 1 : 0;
        }
        __syncthreads();
    }
    if (rank < KKEEP) { keep[i] = 1; pos[i] = rank; idxl[rank] = i; }
    else keep[i] = 0;
}

// sub[r,c] = any(rowbits[idx[r]] & colbits[idx[c]]); bitset rows + degrees.
// One wave per r: lane l holds word l of the row bitset in a register.
__global__ void k_sub(const u64* __restrict__ rowbits, const u64* __restrict__ colbits,
                      const int* __restrict__ idxl, u64* __restrict__ subbits,
                      float* __restrict__ invdeg) {
    int wave = threadIdx.x >> 6, lane = threadIdx.x & 63;
    int r = blockIdx.x * 4 + wave;
    if (r >= KKEEP) return;
    u64 rw = rowbits[(size_t)idxl[r] * 64 + lane];
    int cnt = 0;
    for (int wj = 0; wj < SUBW; ++wj) {
        u64 bits = 0;
        for (int b = 0; b < 64; ++b) {
            int c = wj * 64 + b;
            if (c < KKEEP) {
                u64 cb = colbits[(size_t)idxl[c] * 64 + lane];
                int anyv = __any((rw & cb) != 0ull) ? 1 : 0;
                bits |= ((u64)anyv) << b;
                cnt += anyv;
            }
        }
        if (lane == 0) subbits[(size_t)r * SUBW + wj] = bits;
    }
    if (lane == 0) invdeg[r] = 1.0f / (float)cnt;
}

// t[r] = (h0[idx[r]] * scores[idx[r]]) @ Wb
__global__ void k_t(const float* __restrict__ h0, const float* __restrict__ scores,
                    const int* __restrict__ idxl, const float* __restrict__ Wb,
                    float* __restrict__ t) {
    __shared__ float row[DD];
    int r = blockIdx.x, d = threadIdx.x;
    int i = idxl[r];
    row[d] = h0[(size_t)i * DD + d] * scores[i];
    __syncthreads();
    float acc = 0.f;
    #pragma unroll 4
    for (int k = 0; k < DD; ++k) acc += row[k] * Wb[k * DD + d];
    t[(size_t)r * DD + d] = acc;
}

// hb[r] = sum_{c: sub[r,c]} t[c] * invdeg[c]  + bb
__global__ void k_hb(const u64* __restrict__ subbits, const float* __restrict__ t,
                     const float* __restrict__ invdeg, const float* __restrict__ bb,
                     float* __restrict__ hb) {
    int r = blockIdx.x, d = threadIdx.x;
    float acc = bb[d];
    for (int wj = 0; wj < SUBW; ++wj) {
        u64 wd = subbits[(size_t)r * SUBW + wj];
        while (wd) {
            int b = __builtin_ctzll(wd);
            wd &= wd - 1;
            int c = wj * 64 + b;
            acc += t[(size_t)c * DD + d] * invdeg[c];
        }
    }
    hb[(size_t)r * DD + d] = acc;
}

// uu[r] = hb[r] @ Wu
__global__ void k_u(const float* __restrict__ hb, const float* __restrict__ Wu,
                    float* __restrict__ uu) {
    __shared__ float row[DD];
    int r = blockIdx.x, d = threadIdx.x;
    row[d] = hb[(size_t)r * DD + d];
    __syncthreads();
    float acc = 0.f;
    #pragma unroll 4
    for (int k = 0; k < DD; ++k) acc += row[k] * Wu[k * DD + d];
    uu[(size_t)r * DD + d] = acc;
}

// hup[src] += uu[pos[dst]] per edge (adjacency with multiplicity)
__global__ void k_prop(const int* __restrict__ g, int E, const int* __restrict__ keep,
                       const int* __restrict__ pos, const float* __restrict__ uu,
                       float* __restrict__ hup) {
    int e = blockIdx.x * 2 + (threadIdx.x >> 7);
    int d = threadIdx.x & 127;
    if (e >= E) return;
    int dd = g[E + e];
    if (!keep[dd]) return;
    int s = g[e];
    atomicAdd(&hup[(size_t)s * DD + d], uu[(size_t)pos[dd] * DD + d]);
}

// out1 = hup + bu + h0 ; out2 = out1 + h
__global__ void k_final(const float* __restrict__ hup, const float* __restrict__ bu,
                        const float* __restrict__ h0, const float* __restrict__ h,
                        float* __restrict__ out) {
    int r = blockIdx.x, d = threadIdx.x;
    size_t o = (size_t)r * DD + d;
    float a = hup[o] + bu[d] + h0[o];
    out[o] = a;
    out[(size_t)NN * DD + o] = a + h[o];
}

extern "C" void kernel_launch(void* const* d_in, const int* in_sizes, int n_in,
                              void* d_out, int out_size, void* d_ws, size_t ws_size,
                              hipStream_t stream) {
    const int*   g  = (const int*)d_in[0];
    const float* h  = (const float*)d_in[1];
    const float* Wd = (const float*)d_in[2];
    const float* bd = (const float*)d_in[3];
    const float* pw = (const float*)d_in[4];
    const float* pb = (const float*)d_in[5];
    const float* Wb = (const float*)d_in[6];
    const float* bb = (const float*)d_in[7];
    const float* Wu = (const float*)d_in[8];
    const float* bu = (const float*)d_in[9];
    float* out = (float*)d_out;
    const int E = in_sizes[0] / 2;

    char* ws = (char*)d_ws;
    u64*   rowbits = (u64*)(ws + 0);                 // 2 MB
    u64*   colbits = (u64*)(ws + (2u << 20));        // 2 MB
    u64*   subbits = (u64*)(ws + (4u << 20));        // < 1 MB
    float* h0      = (float*)(ws + (5u << 20));      // 2 MB
    float* hup     = (float*)(ws + (7u << 20));      // 2 MB
    float* t       = (float*)(ws + (9u << 20));      // < 1.25 MB
    float* hb      = (float*)(ws + 10747904u);       // < 1.25 MB
    float* uu      = (float*)(ws + 12058624u);       // < 1.25 MB
    float* scores  = (float*)(ws + 13369344u);
    float* invdeg  = (float*)(ws + 13385728u);
    int*   pos     = (int*)  (ws + 13402112u);
    int*   keep    = (int*)  (ws + 13418496u);
    int*   idxl    = (int*)  (ws + 13434880u);

    // zero bitsets (rowbits+colbits contiguous) and hup accumulator
    hipMemsetAsync(rowbits, 0, (4u << 20), stream);
    hipMemsetAsync(hup, 0, (size_t)NN * DD * sizeof(float), stream);

    k_build_bits<<<(E + 255) / 256, 256, 0, stream>>>(g, E, rowbits, colbits);
    k_h0<<<NN, DD, 0, stream>>>(h, Wd, bd, h0);
    k_score<<<NN, DD, 0, stream>>>(h0, pw, pb, scores);
    k_rank<<<NN / 256, 256, 0, stream>>>(scores, keep, pos, idxl);
    k_sub<<<(KKEEP + 3) / 4, 256, 0, stream>>>(rowbits, colbits, idxl, subbits, invdeg);
    k_t<<<KKEEP, DD, 0, stream>>>(h0, scores, idxl, Wb, t);
    k_hb<<<KKEEP, DD, 0, stream>>>(subbits, t, invdeg, bb, hb);
    k_u<<<KKEEP, DD, 0, stream>>>(hb, Wu, uu);
    k_prop<<<E / 2, 256, 0, stream>>>(g, E, keep, pos, uu, hup);
    k_final<<<NN, DD, 0, stream>>>(hup, bu, h0, h, out);
}

// Round 2
// 351.889 us; speedup vs baseline: 3.1322x; 3.1322x over previous
//
#include <hip/hip_runtime.h>
#include <hip/hip_bf16.h>
#include <stdint.h>

// GraphUnet forward, N=4096 nodes, D=128, E=131072 edges, K=2457 kept.
// All inputs/outputs float32. Strategy: bitset 2-hop via neighbor-union
// (reach2[i] = OR of rowbits over out-neighbors), exact-rank top-k
// (order-invariant), sparse edge propagation. No dense NxN matrices.

#define NN 4096
#define DD 128
#define KKEEP 2457              // int(0.6*4096)
#define SUBW 40                 // ceil(KKEEP/64)

typedef unsigned long long u64;

__global__ void k_build_bits(const int* __restrict__ g, int E,
                             u64* __restrict__ rowbits) {
    int e = blockIdx.x * 256 + threadIdx.x;
    if (e >= E) return;
    int s = g[e], d2 = g[E + e];
    atomicOr(&rowbits[(size_t)s * 64 + (d2 >> 6)], 1ull << (d2 & 63));
}

// h0 = h @ Wd + bd
__global__ void k_h0(const float* __restrict__ h, const float* __restrict__ Wd,
                     const float* __restrict__ bd, float* __restrict__ h0) {
    __shared__ float row[DD];
    int r = blockIdx.x, d = threadIdx.x;
    row[d] = h[(size_t)r * DD + d];
    __syncthreads();
    float acc = bd[d];
    #pragma unroll 4
    for (int k = 0; k < DD; ++k) acc += row[k] * Wd[k * DD + d];
    h0[(size_t)r * DD + d] = acc;
}

// scores = sigmoid(h0 @ pw + pb)
__global__ void k_score(const float* __restrict__ h0, const float* __restrict__ pw,
                        const float* __restrict__ pb, float* __restrict__ scores) {
    __shared__ float red[DD];
    int r = blockIdx.x, tid = threadIdx.x;
    red[tid] = h0[(size_t)r * DD + tid] * pw[tid];
    __syncthreads();
    for (int sft = 64; sft > 0; sft >>= 1) {
        if (tid < sft) red[tid] += red[tid + sft];
        __syncthreads();
    }
    if (tid == 0) scores[r] = 1.0f / (1.0f + expf(-(red[0] + pb[0])));
}

// Exact top-k rank (matches jax.lax.top_k: score desc, index asc on ties).
__global__ void k_rank(const float* __restrict__ scores, int* __restrict__ keep,
                       int* __restrict__ pos, int* __restrict__ idxl) {
    __shared__ float chunk[256];
    int i = blockIdx.x * 256 + threadIdx.x;
    float my = scores[i];
    int rank = 0;
    for (int base = 0; base < NN; base += 256) {
        chunk[threadIdx.x] = scores[base + threadIdx.x];
        __syncthreads();
        for (int j = 0; j < 256; ++j) {
            float sj = chunk[j];
            int jj = base + j;
            rank += ((sj > my) || (sj == my && jj < i)) ? 1 : 0;
        }
        __syncthreads();
    }
    if (rank < KKEEP) { keep[i] = 1; pos[i] = rank; idxl[rank] = i; }
    else keep[i] = 0;
}

// reach2[i] = union over out-neighbors m of rowbits[m]; then project to kept
// columns: sub[r,c] = bit idx[c] of reach2[idx[r]].  One wave per r, lane l
// holds word l of the 4096-bit sets.
__global__ void k_sub(const u64* __restrict__ rowbits, const int* __restrict__ idxl,
                      u64* __restrict__ subbits, float* __restrict__ invdeg) {
    int wave = threadIdx.x >> 6, lane = threadIdx.x & 63;
    int r = blockIdx.x * 4 + wave;
    if (r >= KKEEP) return;
    int i = idxl[r];
    u64 rw = rowbits[(size_t)i * 64 + lane];
    u64 acc = 0;
    // union over neighbors (uniform scalar loop over set bits of rw)
    for (int wm = 0; wm < 64; ++wm) {
        u64 w = __shfl(rw, wm);
        while (w) {
            int b = __builtin_ctzll(w);
            w &= w - 1;
            int m = wm * 64 + b;
            acc |= rowbits[(size_t)m * 64 + lane];
        }
    }
    // project 4096-bit reach set -> K-bit sub row
    int cnt = 0;
    for (int wj = 0; wj < SUBW; ++wj) {
        int c = wj * 64 + lane;
        int ci = (c < KKEEP) ? idxl[c] : 0;
        u64 w = __shfl(acc, ci >> 6);                 // variable-lane bpermute
        int bit = (c < KKEEP) ? (int)((w >> (ci & 63)) & 1ull) : 0;
        u64 word = __ballot(bit);
        cnt += __popcll(word);
        if (lane == 0) subbits[(size_t)r * SUBW + wj] = word;
    }
    if (lane == 0) invdeg[r] = 1.0f / (float)cnt;
}

// t[r] = (h0[idx[r]] * scores[idx[r]]) @ Wb
__global__ void k_t(const float* __restrict__ h0, const float* __restrict__ scores,
                    const int* __restrict__ idxl, const float* __restrict__ Wb,
                    float* __restrict__ t) {
    __shared__ float row[DD];
    int r = blockIdx.x, d = threadIdx.x;
    int i = idxl[r];
    row[d] = h0[(size_t)i * DD + d] * scores[i];
    __syncthreads();
    float acc = 0.f;
    #pragma unroll 4
    for (int k = 0; k < DD; ++k) acc += row[k] * Wb[k * DD + d];
    t[(size_t)r * DD + d] = acc;
}

// hb[r] = sum_{c: sub[r,c]} t[c] * invdeg[c]  + bb
__global__ void k_hb(const u64* __restrict__ subbits, const float* __restrict__ t,
                     const float* __restrict__ invdeg, const float* __restrict__ bb,
                     float* __restrict__ hb) {
    int r = blockIdx.x, d = threadIdx.x;
    float acc = bb[d];
    for (int wj = 0; wj < SUBW; ++wj) {
        u64 wd = subbits[(size_t)r * SUBW + wj];
        while (wd) {
            int b = __builtin_ctzll(wd);
            wd &= wd - 1;
            int c = wj * 64 + b;
            acc += t[(size_t)c * DD + d] * invdeg[c];
        }
    }
    hb[(size_t)r * DD + d] = acc;
}

// uu[r] = hb[r] @ Wu
__global__ void k_u(const float* __restrict__ hb, const float* __restrict__ Wu,
                    float* __restrict__ uu) {
    __shared__ float row[DD];
    int r = blockIdx.x, d = threadIdx.x;
    row[d] = hb[(size_t)r * DD + d];
    __syncthreads();
    float acc = 0.f;
    #pragma unroll 4
    for (int k = 0; k < DD; ++k) acc += row[k] * Wu[k * DD + d];
    uu[(size_t)r * DD + d] = acc;
}

// hup[src] += uu[pos[dst]] per edge (adjacency with multiplicity)
__global__ void k_prop(const int* __restrict__ g, int E, const int* __restrict__ keep,
                       const int* __restrict__ pos, const float* __restrict__ uu,
                       float* __restrict__ hup) {
    int e = blockIdx.x * 2 + (threadIdx.x >> 7);
    int d = threadIdx.x & 127;
    if (e >= E) return;
    int dd = g[E + e];
    if (!keep[dd]) return;
    int s = g[e];
    atomicAdd(&hup[(size_t)s * DD + d], uu[(size_t)pos[dd] * DD + d]);
}

// out1 = hup + bu + h0 ; out2 = out1 + h
__global__ void k_final(const float* __restrict__ hup, const float* __restrict__ bu,
                        const float* __restrict__ h0, const float* __restrict__ h,
                        float* __restrict__ out) {
    int r = blockIdx.x, d = threadIdx.x;
    size_t o = (size_t)r * DD + d;
    float a = hup[o] + bu[d] + h0[o];
    out[o] = a;
    out[(size_t)NN * DD + o] = a + h[o];
}

extern "C" void kernel_launch(void* const* d_in, const int* in_sizes, int n_in,
                              void* d_out, int out_size, void* d_ws, size_t ws_size,
                              hipStream_t stream) {
    const int*   g  = (const int*)d_in[0];
    const float* h  = (const float*)d_in[1];
    const float* Wd = (const float*)d_in[2];
    const float* bd = (const float*)d_in[3];
    const float* pw = (const float*)d_in[4];
    const float* pb = (const float*)d_in[5];
    const float* Wb = (const float*)d_in[6];
    const float* bb = (const float*)d_in[7];
    const float* Wu = (const float*)d_in[8];
    const float* bu = (const float*)d_in[9];
    float* out = (float*)d_out;
    const int E = in_sizes[0] / 2;

    char* ws = (char*)d_ws;
    u64*   rowbits = (u64*)(ws + 0);                 // 2 MB
    u64*   subbits = (u64*)(ws + (4u << 20));        // < 1 MB
    float* h0      = (float*)(ws + (5u << 20));      // 2 MB
    float* hup     = (float*)(ws + (7u << 20));      // 2 MB
    float* t       = (float*)(ws + (9u << 20));      // < 1.25 MB
    float* hb      = (float*)(ws + 10747904u);       // < 1.25 MB
    float* uu      = (float*)(ws + 12058624u);       // < 1.25 MB
    float* scores  = (float*)(ws + 13369344u);
    float* invdeg  = (float*)(ws + 13385728u);
    int*   pos     = (int*)  (ws + 13402112u);
    int*   keep    = (int*)  (ws + 13418496u);
    int*   idxl    = (int*)  (ws + 13434880u);

    hipMemsetAsync(rowbits, 0, (2u << 20), stream);
    hipMemsetAsync(hup, 0, (size_t)NN * DD * sizeof(float), stream);

    k_build_bits<<<(E + 255) / 256, 256, 0, stream>>>(g, E, rowbits);
    k_h0<<<NN, DD, 0, stream>>>(h, Wd, bd, h0);
    k_score<<<NN, DD, 0, stream>>>(h0, pw, pb, scores);
    k_rank<<<NN / 256, 256, 0, stream>>>(scores, keep, pos, idxl);
    k_sub<<<(KKEEP + 3) / 4, 256, 0, stream>>>(rowbits, idxl, subbits, invdeg);
    k_t<<<KKEEP, DD, 0, stream>>>(h0, scores, idxl, Wb, t);
    k_hb<<<KKEEP, DD, 0, stream>>>(subbits, t, invdeg, bb, hb);
    k_u<<<KKEEP, DD, 0, stream>>>(hb, Wu, uu);
    k_prop<<<E / 2, 256, 0, stream>>>(g, E, keep, pos, uu, hup);
    k_final<<<NN, DD, 0, stream>>>(hup, bu, h0, h, out);
}

// Round 4
// 278.110 us; speedup vs baseline: 3.9631x; 1.2653x over previous
//
#include <hip/hip_runtime.h>
#include <hip/hip_bf16.h>
#include <stdint.h>

// GraphUnet forward, N=4096 nodes, D=128, E=131072 edges, K=2457 kept.
// Bitset 2-hop via neighbor-union; exact-rank top-k; pooled GCN as dense
// bf16 MFMA GEMM over a binary connectivity matrix; sparse edge prop.

#define NN 4096
#define DD 128
#define KKEEP 2457              // int(0.6*4096)
#define SUBW 40                 // ceil(KKEEP/64)
#define MP 2464                 // KKEEP padded to 16 (M tiles = 154)
#define KP 2560                 // KKEEP padded to SUBW*64 (80 k-steps of 32)
#define MT 154
#define NT 8
#define SPLITK 4
#define KCHUNK (KP / SPLITK)    // 640 -> 20 mfma steps per wave

typedef unsigned long long u64;
typedef unsigned short ushort_t;
typedef __attribute__((ext_vector_type(8))) short bf16x8;
typedef __attribute__((ext_vector_type(4))) float f32x4;

__global__ void k_build_bits(const int* __restrict__ g, int E,
                             u64* __restrict__ rowbits) {
    int e = blockIdx.x * 256 + threadIdx.x;
    if (e >= E) return;
    int s = g[e], d2 = g[E + e];
    atomicOr(&rowbits[(size_t)s * 64 + (d2 >> 6)], 1ull << (d2 & 63));
}

// h0 = h @ Wd + bd
__global__ void k_h0(const float* __restrict__ h, const float* __restrict__ Wd,
                     const float* __restrict__ bd, float* __restrict__ h0) {
    __shared__ float row[DD];
    int r = blockIdx.x, d = threadIdx.x;
    row[d] = h[(size_t)r * DD + d];
    __syncthreads();
    float acc = bd[d];
    #pragma unroll 4
    for (int k = 0; k < DD; ++k) acc += row[k] * Wd[k * DD + d];
    h0[(size_t)r * DD + d] = acc;
}

// scores = sigmoid(h0 @ pw + pb)
__global__ void k_score(const float* __restrict__ h0, const float* __restrict__ pw,
                        const float* __restrict__ pb, float* __restrict__ scores) {
    __shared__ float red[DD];
    int r = blockIdx.x, tid = threadIdx.x;
    red[tid] = h0[(size_t)r * DD + tid] * pw[tid];
    __syncthreads();
    for (int sft = 64; sft > 0; sft >>= 1) {
        if (tid < sft) red[tid] += red[tid + sft];
        __syncthreads();
    }
    if (tid == 0) scores[r] = 1.0f / (1.0f + expf(-(red[0] + pb[0])));
}

// Exact top-k rank (matches jax.lax.top_k: score desc, index asc on ties).
__global__ void k_rank(const float* __restrict__ scores, int* __restrict__ keep,
                       int* __restrict__ pos, int* __restrict__ idxl) {
    __shared__ float chunk[256];
    int i = blockIdx.x * 256 + threadIdx.x;
    float my = scores[i];
    int rank = 0;
    for (int base = 0; base < NN; base += 256) {
        chunk[threadIdx.x] = scores[base + threadIdx.x];
        __syncthreads();
        for (int j = 0; j < 256; ++j) {
            float sj = chunk[j];
            int jj = base + j;
            rank += ((sj > my) || (sj == my && jj < i)) ? 1 : 0;
        }
        __syncthreads();
    }
    if (rank < KKEEP) { keep[i] = 1; pos[i] = rank; idxl[rank] = i; }
    else keep[i] = 0;
}

// reach2[i] = union over out-neighbors m of rowbits[m]; project to kept cols.
__global__ void k_sub(const u64* __restrict__ rowbits, const int* __restrict__ idxl,
                      u64* __restrict__ subbits, float* __restrict__ invdeg) {
    int wave = threadIdx.x >> 6, lane = threadIdx.x & 63;
    int r = blockIdx.x * 4 + wave;
    if (r >= KKEEP) return;
    int i = idxl[r];
    u64 rw = rowbits[(size_t)i * 64 + lane];
    u64 acc = 0;
    for (int wm = 0; wm < 64; ++wm) {
        u64 w = __shfl(rw, wm);
        while (w) {
            int b = __builtin_ctzll(w);
            w &= w - 1;
            int m = wm * 64 + b;
            acc |= rowbits[(size_t)m * 64 + lane];
        }
    }
    int cnt = 0;
    for (int wj = 0; wj < SUBW; ++wj) {
        int c = wj * 64 + lane;
        int ci = (c < KKEEP) ? idxl[c] : 0;
        u64 w = __shfl(acc, ci >> 6);
        int bit = (c < KKEEP) ? (int)((w >> (ci & 63)) & 1ull) : 0;
        u64 word = __ballot(bit);
        cnt += __popcll(word);
        if (lane == 0) subbits[(size_t)r * SUBW + wj] = word;
    }
    if (lane == 0) invdeg[r] = 1.0f / (float)cnt;
}

// Expand subbits -> dense bf16 binary matrix S [MP][KP] (1.0 or 0.0).
__global__ void k_expand(const u64* __restrict__ subbits, short* __restrict__ S) {
    int r = blockIdx.x;
    int t = threadIdx.x;
    u64* Srow = (u64*)(S + (size_t)r * KP);
    bool live = (r < KKEEP);
    #pragma unroll
    for (int i = 0; i < 2; ++i) {
        int q = t + i * 320;              // quad of 4 bf16 = 8 bytes
        if (q >= KP / 4) break;
        u64 outw = 0;
        if (live) {
            int c0 = q * 4;
            u64 w = subbits[(size_t)r * SUBW + (c0 >> 6)];
            int sh = c0 & 63;
            if ((w >> sh) & 1)       outw |= 0x3F80ull;
            if ((w >> (sh + 1)) & 1) outw |= 0x3F80ull << 16;
            if ((w >> (sh + 2)) & 1) outw |= 0x3F80ull << 32;
            if ((w >> (sh + 3)) & 1) outw |= 0x3F80ull << 48;
        }
        Srow[q] = outw;
    }
}

// t'[c] = (h0[idx[c]] * scores[idx[c]]) @ Wb * invdeg[c], stored transposed bf16.
__global__ void k_t(const float* __restrict__ h0, const float* __restrict__ scores,
                    const int* __restrict__ idxl, const float* __restrict__ Wb,
                    const float* __restrict__ invdeg, ushort_t* __restrict__ tT) {
    __shared__ float row[DD];
    int r = blockIdx.x, d = threadIdx.x;
    int i = idxl[r];
    row[d] = h0[(size_t)i * DD + d] * scores[i];
    __syncthreads();
    float acc = 0.f;
    #pragma unroll 4
    for (int k = 0; k < DD; ++k) acc += row[k] * Wb[k * DD + d];
    float v = acc * invdeg[r];
    __hip_bfloat16 b = __float2bfloat16(v);
    tT[(size_t)d * KP + r] = *reinterpret_cast<ushort_t*>(&b);
}

// hb = S @ t' via 16x16x32 bf16 MFMA, split-K=4 with f32 atomics.
__global__ void k_gemm(const short* __restrict__ S, const short* __restrict__ tT,
                       float* __restrict__ hb) {
    int wid = blockIdx.x * 4 + (threadIdx.x >> 6);
    int lane = threadIdx.x & 63;
    int tile = wid % (MT * NT);
    int sk = wid / (MT * NT);
    int rt = tile >> 3, ct = tile & 7;
    const short* arow = S + (size_t)(rt * 16 + (lane & 15)) * KP + ((lane >> 4) * 8) + sk * KCHUNK;
    const short* brow = tT + (size_t)(ct * 16 + (lane & 15)) * KP + ((lane >> 4) * 8) + sk * KCHUNK;
    f32x4 acc = {0.f, 0.f, 0.f, 0.f};
    #pragma unroll 4
    for (int kk = 0; kk < KCHUNK; kk += 32) {
        bf16x8 a = *(const bf16x8*)(arow + kk);
        bf16x8 b = *(const bf16x8*)(brow + kk);
        acc = __builtin_amdgcn_mfma_f32_16x16x32_bf16(a, b, acc, 0, 0, 0);
    }
    int col = ct * 16 + (lane & 15);
    int row0 = rt * 16 + ((lane >> 4) * 4);
    #pragma unroll
    for (int j = 0; j < 4; ++j) {
        int row = row0 + j;
        if (row < KKEEP) atomicAdd(&hb[(size_t)row * DD + col], acc[j]);
    }
}

// uu[r] = (hb[r] + bb) @ Wu
__global__ void k_u(const float* __restrict__ hb, const float* __restrict__ bb,
                    const float* __restrict__ Wu, float* __restrict__ uu) {
    __shared__ float row[DD];
    int r = blockIdx.x, d = threadIdx.x;
    row[d] = hb[(size_t)r * DD + d] + bb[d];
    __syncthreads();
    float acc = 0.f;
    #pragma unroll 4
    for (int k = 0; k < DD; ++k) acc += row[k] * Wu[k * DD + d];
    uu[(size_t)r * DD + d] = acc;
}

// hup[src] += uu[pos[dst]] per edge (adjacency with multiplicity)
__global__ void k_prop(const int* __restrict__ g, int E, const int* __restrict__ keep,
                       const int* __restrict__ pos, const float* __restrict__ uu,
                       float* __restrict__ hup) {
    int e = blockIdx.x * 2 + (threadIdx.x >> 7);
    int d = threadIdx.x & 127;
    if (e >= E) return;
    int dd = g[E + e];
    if (!keep[dd]) return;
    int s = g[e];
    atomicAdd(&hup[(size_t)s * DD + d], uu[(size_t)pos[dd] * DD + d]);
}

// out1 = hup + bu + h0 ; out2 = out1 + h
__global__ void k_final(const float* __restrict__ hup, const float* __restrict__ bu,
                        const float* __restrict__ h0, const float* __restrict__ h,
                        float* __restrict__ out) {
    int r = blockIdx.x, d = threadIdx.x;
    size_t o = (size_t)r * DD + d;
    float a = hup[o] + bu[d] + h0[o];
    out[o] = a;
    out[(size_t)NN * DD + o] = a + h[o];
}

extern "C" void kernel_launch(void* const* d_in, const int* in_sizes, int n_in,
                              void* d_out, int out_size, void* d_ws, size_t ws_size,
                              hipStream_t stream) {
    const int*   g  = (const int*)d_in[0];
    const float* h  = (const float*)d_in[1];
    const float* Wd = (const float*)d_in[2];
    const float* bd = (const float*)d_in[3];
    const float* pw = (const float*)d_in[4];
    const float* pb = (const float*)d_in[5];
    const float* Wb = (const float*)d_in[6];
    const float* bb = (const float*)d_in[7];
    const float* Wu = (const float*)d_in[8];
    const float* bu = (const float*)d_in[9];
    float* out = (float*)d_out;
    const int E = in_sizes[0] / 2;

    char* ws = (char*)d_ws;
    // S occupies [0, ~12.6MB); rowbits [0,2MB) dies before k_expand writes S;
    // uu reuses [0,1.3MB) after k_gemm has consumed S.
    short*    S       = (short*)(ws + 0);
    u64*      rowbits = (u64*)  (ws + 0);
    float*    uu      = (float*)(ws + 0);
    u64*      subbits = (u64*)  (ws + (13u << 20));   // 786 KB
    float*    h0      = (float*)(ws + (14u << 20));   // 2 MB
    float*    hup     = (float*)(ws + (16u << 20));   // 2 MB
    ushort_t* tT      = (ushort_t*)(ws + (18u << 20));// 656 KB
    float*    hb      = (float*)(ws + (19u << 20));   // 1.26 MB
    float*    scores  = (float*)(ws + (21u << 20));
    float*    invdeg  = (float*)(ws + (21u << 20) + 16384);
    int*      pos     = (int*)  (ws + (21u << 20) + 32768);
    int*      keep    = (int*)  (ws + (21u << 20) + 49152);
    int*      idxl    = (int*)  (ws + (21u << 20) + 65536);

    (void)hipMemsetAsync(rowbits, 0, (2u << 20), stream);
    (void)hipMemsetAsync(hup, 0, (size_t)NN * DD * sizeof(float), stream);
    (void)hipMemsetAsync(tT, 0, (size_t)DD * KP * sizeof(ushort_t), stream);
    (void)hipMemsetAsync(hb, 0, (size_t)KKEEP * DD * sizeof(float), stream);

    k_build_bits<<<(E + 255) / 256, 256, 0, stream>>>(g, E, rowbits);
    k_h0<<<NN, DD, 0, stream>>>(h, Wd, bd, h0);
    k_score<<<NN, DD, 0, stream>>>(h0, pw, pb, scores);
    k_rank<<<NN / 256, 256, 0, stream>>>(scores, keep, pos, idxl);
    k_sub<<<(KKEEP + 3) / 4, 256, 0, stream>>>(rowbits, idxl, subbits, invdeg);
    k_expand<<<MP, 320, 0, stream>>>(subbits, S);
    k_t<<<KKEEP, DD, 0, stream>>>(h0, scores, idxl, Wb, invdeg, tT);
    k_gemm<<<(MT * NT * SPLITK) / 4, 256, 0, stream>>>(S, (const short*)tT, hb);
    k_u<<<KKEEP, DD, 0, stream>>>(hb, bb, Wu, uu);
    k_prop<<<E / 2, 256, 0, stream>>>(g, E, keep, pos, uu, hup);
    k_final<<<NN, DD, 0, stream>>>(hup, bu, h0, h, out);
}

// Round 5
// 176.469 us; speedup vs baseline: 6.2457x; 1.5760x over previous
//
#include <hip/hip_runtime.h>
#include <hip/hip_bf16.h>
#include <stdint.h>

// GraphUnet forward, N=4096 nodes, D=128, E=131072 edges, K=2457 kept.
// Bitset 2-hop via neighbor-union; exact-rank top-k (wave-parallel);
// pooled GCN as dense bf16 MFMA GEMM over a binary matrix; sparse edge prop.

#define NN 4096
#define DD 128
#define KKEEP 2457              // int(0.6*4096)
#define SUBW 40                 // ceil(KKEEP/64)
#define MP 2464                 // KKEEP padded to 16 (M tiles = 154)
#define KP 2560                 // KKEEP padded to SUBW*64 (80 k-steps of 32)
#define MT 154
#define NT 8
#define SPLITK 4
#define KCHUNK (KP / SPLITK)    // 640 -> 20 mfma steps per wave

typedef unsigned long long u64;
typedef unsigned short ushort_t;
typedef __attribute__((ext_vector_type(8))) short bf16x8;
typedef __attribute__((ext_vector_type(4))) float f32x4;

__global__ void k_build_bits(const int* __restrict__ g, int E,
                             u64* __restrict__ rowbits) {
    int e = blockIdx.x * 256 + threadIdx.x;
    if (e >= E) return;
    int s = g[e], d2 = g[E + e];
    atomicOr(&rowbits[(size_t)s * 64 + (d2 >> 6)], 1ull << (d2 & 63));
}

// h0 = h @ Wd + bd
__global__ void k_h0(const float* __restrict__ h, const float* __restrict__ Wd,
                     const float* __restrict__ bd, float* __restrict__ h0) {
    __shared__ float row[DD];
    int r = blockIdx.x, d = threadIdx.x;
    row[d] = h[(size_t)r * DD + d];
    __syncthreads();
    float acc = bd[d];
    #pragma unroll 4
    for (int k = 0; k < DD; ++k) acc += row[k] * Wd[k * DD + d];
    h0[(size_t)r * DD + d] = acc;
}

// scores = sigmoid(h0 @ pw + pb)
__global__ void k_score(const float* __restrict__ h0, const float* __restrict__ pw,
                        const float* __restrict__ pb, float* __restrict__ scores) {
    __shared__ float red[DD];
    int r = blockIdx.x, tid = threadIdx.x;
    red[tid] = h0[(size_t)r * DD + tid] * pw[tid];
    __syncthreads();
    for (int sft = 64; sft > 0; sft >>= 1) {
        if (tid < sft) red[tid] += red[tid + sft];
        __syncthreads();
    }
    if (tid == 0) scores[r] = 1.0f / (1.0f + expf(-(red[0] + pb[0])));
}

// Exact top-k rank, one wave per node i. rank = #{j: s_j>s_i or (s_j==s_i, j<i)}.
__global__ void k_rank(const float* __restrict__ scores, int* __restrict__ keep,
                       int* __restrict__ pos, int* __restrict__ idxl) {
    int lane = threadIdx.x & 63;
    int i = blockIdx.x * 4 + (threadIdx.x >> 6);      // node for this wave
    float my = scores[i];
    int rank = 0;
    #pragma unroll 4
    for (int base = 0; base < NN; base += 64) {
        int jj = base + lane;
        float sj = scores[jj];
        u64 m = __ballot((sj > my) || (sj == my && jj < i));
        rank += __popcll(m);
    }
    if (lane == 0) {
        if (rank < KKEEP) { keep[i] = 1; pos[i] = rank; idxl[rank] = i; }
        else keep[i] = 0;
    }
}

// reach2[i] = union over out-neighbors m of rowbits[m]; project to kept cols.
__global__ void k_sub(const u64* __restrict__ rowbits, const int* __restrict__ idxl,
                      u64* __restrict__ subbits, float* __restrict__ invdeg) {
    int wave = threadIdx.x >> 6, lane = threadIdx.x & 63;
    int r = blockIdx.x * 4 + wave;
    if (r >= KKEEP) return;
    int i = idxl[r];
    u64 rw = rowbits[(size_t)i * 64 + lane];
    u64 acc = 0;
    for (int wm = 0; wm < 64; ++wm) {
        u64 w = __shfl(rw, wm);
        while (w) {
            int b = __builtin_ctzll(w);
            w &= w - 1;
            int m = wm * 64 + b;
            acc |= rowbits[(size_t)m * 64 + lane];
        }
    }
    int cnt = 0;
    for (int wj = 0; wj < SUBW; ++wj) {
        int c = wj * 64 + lane;
        int ci = (c < KKEEP) ? idxl[c] : 0;
        u64 w = __shfl(acc, ci >> 6);
        int bit = (c < KKEEP) ? (int)((w >> (ci & 63)) & 1ull) : 0;
        u64 word = __ballot(bit);
        cnt += __popcll(word);
        if (lane == 0) subbits[(size_t)r * SUBW + wj] = word;
    }
    if (lane == 0) invdeg[r] = 1.0f / (float)cnt;
}

// Expand subbits -> dense bf16 binary matrix S [MP][KP] (1.0 or 0.0).
__global__ void k_expand(const u64* __restrict__ subbits, short* __restrict__ S) {
    int r = blockIdx.x;
    int t = threadIdx.x;
    u64* Srow = (u64*)(S + (size_t)r * KP);
    bool live = (r < KKEEP);
    #pragma unroll
    for (int i = 0; i < 2; ++i) {
        int q = t + i * 320;              // quad of 4 bf16 = 8 bytes
        if (q >= KP / 4) break;
        u64 outw = 0;
        if (live) {
            int c0 = q * 4;
            u64 w = subbits[(size_t)r * SUBW + (c0 >> 6)];
            int sh = c0 & 63;
            if ((w >> sh) & 1)       outw |= 0x3F80ull;
            if ((w >> (sh + 1)) & 1) outw |= 0x3F80ull << 16;
            if ((w >> (sh + 2)) & 1) outw |= 0x3F80ull << 32;
            if ((w >> (sh + 3)) & 1) outw |= 0x3F80ull << 48;
        }
        Srow[q] = outw;
    }
}

// t'[c] = (h0[idx[c]] * scores[idx[c]]) @ Wb * invdeg[c], stored transposed bf16.
__global__ void k_t(const float* __restrict__ h0, const float* __restrict__ scores,
                    const int* __restrict__ idxl, const float* __restrict__ Wb,
                    const float* __restrict__ invdeg, ushort_t* __restrict__ tT) {
    __shared__ float row[DD];
    int r = blockIdx.x, d = threadIdx.x;
    int i = idxl[r];
    row[d] = h0[(size_t)i * DD + d] * scores[i];
    __syncthreads();
    float acc = 0.f;
    #pragma unroll 4
    for (int k = 0; k < DD; ++k) acc += row[k] * Wb[k * DD + d];
    float v = acc * invdeg[r];
    __hip_bfloat16 b = __float2bfloat16(v);
    tT[(size_t)d * KP + r] = *reinterpret_cast<ushort_t*>(&b);
}

// hb = S @ t' via 16x16x32 bf16 MFMA, split-K=4 with f32 atomics.
__global__ void k_gemm(const short* __restrict__ S, const short* __restrict__ tT,
                       float* __restrict__ hb) {
    int wid = blockIdx.x * 4 + (threadIdx.x >> 6);
    int lane = threadIdx.x & 63;
    int tile = wid % (MT * NT);
    int sk = wid / (MT * NT);
    int rt = tile >> 3, ct = tile & 7;
    const short* arow = S + (size_t)(rt * 16 + (lane & 15)) * KP + ((lane >> 4) * 8) + sk * KCHUNK;
    const short* brow = tT + (size_t)(ct * 16 + (lane & 15)) * KP + ((lane >> 4) * 8) + sk * KCHUNK;
    f32x4 acc = {0.f, 0.f, 0.f, 0.f};
    #pragma unroll 4
    for (int kk = 0; kk < KCHUNK; kk += 32) {
        bf16x8 a = *(const bf16x8*)(arow + kk);
        bf16x8 b = *(const bf16x8*)(brow + kk);
        acc = __builtin_amdgcn_mfma_f32_16x16x32_bf16(a, b, acc, 0, 0, 0);
    }
    int col = ct * 16 + (lane & 15);
    int row0 = rt * 16 + ((lane >> 4) * 4);
    #pragma unroll
    for (int j = 0; j < 4; ++j) {
        int row = row0 + j;
        if (row < KKEEP) atomicAdd(&hb[(size_t)row * DD + col], acc[j]);
    }
}

// uu[r] = (hb[r] + bb) @ Wu
__global__ void k_u(const float* __restrict__ hb, const float* __restrict__ bb,
                    const float* __restrict__ Wu, float* __restrict__ uu) {
    __shared__ float row[DD];
    int r = blockIdx.x, d = threadIdx.x;
    row[d] = hb[(size_t)r * DD + d] + bb[d];
    __syncthreads();
    float acc = 0.f;
    #pragma unroll 4
    for (int k = 0; k < DD; ++k) acc += row[k] * Wu[k * DD + d];
    uu[(size_t)r * DD + d] = acc;
}

// hup[src] += uu[pos[dst]] per edge (adjacency with multiplicity)
__global__ void k_prop(const int* __restrict__ g, int E, const int* __restrict__ keep,
                       const int* __restrict__ pos, const float* __restrict__ uu,
                       float* __restrict__ hup) {
    int e = blockIdx.x * 2 + (threadIdx.x >> 7);
    int d = threadIdx.x & 127;
    if (e >= E) return;
    int dd = g[E + e];
    if (!keep[dd]) return;
    int s = g[e];
    atomicAdd(&hup[(size_t)s * DD + d], uu[(size_t)pos[dd] * DD + d]);
}

// out1 = hup + bu + h0 ; out2 = out1 + h
__global__ void k_final(const float* __restrict__ hup, const float* __restrict__ bu,
                        const float* __restrict__ h0, const float* __restrict__ h,
                        float* __restrict__ out) {
    int r = blockIdx.x, d = threadIdx.x;
    size_t o = (size_t)r * DD + d;
    float a = hup[o] + bu[d] + h0[o];
    out[o] = a;
    out[(size_t)NN * DD + o] = a + h[o];
}

extern "C" void kernel_launch(void* const* d_in, const int* in_sizes, int n_in,
                              void* d_out, int out_size, void* d_ws, size_t ws_size,
                              hipStream_t stream) {
    const int*   g  = (const int*)d_in[0];
    const float* h  = (const float*)d_in[1];
    const float* Wd = (const float*)d_in[2];
    const float* bd = (const float*)d_in[3];
    const float* pw = (const float*)d_in[4];
    const float* pb = (const float*)d_in[5];
    const float* Wb = (const float*)d_in[6];
    const float* bb = (const float*)d_in[7];
    const float* Wu = (const float*)d_in[8];
    const float* bu = (const float*)d_in[9];
    float* out = (float*)d_out;
    const int E = in_sizes[0] / 2;

    char* ws = (char*)d_ws;
    // S occupies [0, ~12.6MB); rowbits [0,2MB) dies before k_expand writes S;
    // uu reuses [0,1.3MB) after k_gemm has consumed S.
    short*    S       = (short*)(ws + 0);
    u64*      rowbits = (u64*)  (ws + 0);
    float*    uu      = (float*)(ws + 0);
    u64*      subbits = (u64*)  (ws + (13u << 20));   // 786 KB
    float*    h0      = (float*)(ws + (14u << 20));   // 2 MB
    float*    hup     = (float*)(ws + (16u << 20));   // 2 MB
    ushort_t* tT      = (ushort_t*)(ws + (18u << 20));// 656 KB
    float*    hb      = (float*)(ws + (19u << 20));   // 1.26 MB
    float*    scores  = (float*)(ws + (21u << 20));
    float*    invdeg  = (float*)(ws + (21u << 20) + 16384);
    int*      pos     = (int*)  (ws + (21u << 20) + 32768);
    int*      keep    = (int*)  (ws + (21u << 20) + 49152);
    int*      idxl    = (int*)  (ws + (21u << 20) + 65536);

    (void)hipMemsetAsync(rowbits, 0, (2u << 20), stream);
    (void)hipMemsetAsync(hup, 0, (size_t)NN * DD * sizeof(float), stream);
    (void)hipMemsetAsync(tT, 0, (size_t)DD * KP * sizeof(ushort_t), stream);
    (void)hipMemsetAsync(hb, 0, (size_t)KKEEP * DD * sizeof(float), stream);

    k_build_bits<<<(E + 255) / 256, 256, 0, stream>>>(g, E, rowbits);
    k_h0<<<NN, DD, 0, stream>>>(h, Wd, bd, h0);
    k_score<<<NN, DD, 0, stream>>>(h0, pw, pb, scores);
    k_rank<<<NN / 4, 256, 0, stream>>>(scores, keep, pos, idxl);
    k_sub<<<(KKEEP + 3) / 4, 256, 0, stream>>>(rowbits, idxl, subbits, invdeg);
    k_expand<<<MP, 320, 0, stream>>>(subbits, S);
    k_t<<<KKEEP, DD, 0, stream>>>(h0, scores, idxl, Wb, invdeg, tT);
    k_gemm<<<(MT * NT * SPLITK) / 4, 256, 0, stream>>>(S, (const short*)tT, hb);
    k_u<<<KKEEP, DD, 0, stream>>>(hb, bb, Wu, uu);
    k_prop<<<E / 2, 256, 0, stream>>>(g, E, keep, pos, uu, hup);
    k_final<<<NN, DD, 0, stream>>>(hup, bu, h0, h, out);
}

// Round 6
// 153.809 us; speedup vs baseline: 7.1658x; 1.1473x over previous
//
#include <hip/hip_runtime.h>
#include <hip/hip_bf16.h>
#include <stdint.h>

// GraphUnet forward, N=4096 nodes, D=128, E=131072 edges, K=2457 kept.
// Bitset 2-hop via neighbor-union; exact-rank top-k (wave-parallel);
// pooled GCN as dense bf16 MFMA GEMM over a binary matrix; up-propagation
// via kept-edge CSR gather (no float atomics), fused with the final adds.

#define NN 4096
#define DD 128
#define KKEEP 2457              // int(0.6*4096)
#define SUBW 40                 // ceil(KKEEP/64)
#define MP 2464                 // KKEEP padded to 16 (M tiles = 154)
#define KP 2560                 // KKEEP padded to SUBW*64 (80 k-steps of 32)
#define MT 154
#define NT 8
#define SPLITK 4
#define KCHUNK (KP / SPLITK)    // 640 -> 20 mfma steps per wave

typedef unsigned long long u64;
typedef unsigned short ushort_t;
typedef __attribute__((ext_vector_type(8))) short bf16x8;
typedef __attribute__((ext_vector_type(4))) float f32x4;

__global__ void k_build_bits(const int* __restrict__ g, int E,
                             u64* __restrict__ rowbits) {
    int e = blockIdx.x * 256 + threadIdx.x;
    if (e >= E) return;
    int s = g[e], d2 = g[E + e];
    atomicOr(&rowbits[(size_t)s * 64 + (d2 >> 6)], 1ull << (d2 & 63));
}

// h0 = h @ Wd + bd
__global__ void k_h0(const float* __restrict__ h, const float* __restrict__ Wd,
                     const float* __restrict__ bd, float* __restrict__ h0) {
    __shared__ float row[DD];
    int r = blockIdx.x, d = threadIdx.x;
    row[d] = h[(size_t)r * DD + d];
    __syncthreads();
    float acc = bd[d];
    #pragma unroll 4
    for (int k = 0; k < DD; ++k) acc += row[k] * Wd[k * DD + d];
    h0[(size_t)r * DD + d] = acc;
}

// scores = sigmoid(h0 @ pw + pb)
__global__ void k_score(const float* __restrict__ h0, const float* __restrict__ pw,
                        const float* __restrict__ pb, float* __restrict__ scores) {
    __shared__ float red[DD];
    int r = blockIdx.x, tid = threadIdx.x;
    red[tid] = h0[(size_t)r * DD + tid] * pw[tid];
    __syncthreads();
    for (int sft = 64; sft > 0; sft >>= 1) {
        if (tid < sft) red[tid] += red[tid + sft];
        __syncthreads();
    }
    if (tid == 0) scores[r] = 1.0f / (1.0f + expf(-(red[0] + pb[0])));
}

// Exact top-k rank, one wave per node i. rank = #{j: s_j>s_i or (s_j==s_i, j<i)}.
__global__ void k_rank(const float* __restrict__ scores, int* __restrict__ keep,
                       int* __restrict__ pos, int* __restrict__ idxl) {
    int lane = threadIdx.x & 63;
    int i = blockIdx.x * 4 + (threadIdx.x >> 6);      // node for this wave
    float my = scores[i];
    int rank = 0;
    #pragma unroll 4
    for (int base = 0; base < NN; base += 64) {
        int jj = base + lane;
        float sj = scores[jj];
        u64 m = __ballot((sj > my) || (sj == my && jj < i));
        rank += __popcll(m);
    }
    if (lane == 0) {
        if (rank < KKEEP) { keep[i] = 1; pos[i] = rank; idxl[rank] = i; }
        else keep[i] = 0;
    }
}

// kept-edge degree histogram by src
__global__ void k_deg(const int* __restrict__ g, int E, const int* __restrict__ keep,
                      int* __restrict__ deg) {
    int e = blockIdx.x * 256 + threadIdx.x;
    if (e >= E) return;
    if (keep[g[E + e]]) atomicAdd(&deg[g[e]], 1);
}

// exclusive scan of deg[NN] -> off[NN+1]; single block of 256 threads x 16 each
__global__ void k_scan(const int* __restrict__ deg, int* __restrict__ off) {
    __shared__ int part[256];
    int t = threadIdx.x;
    int base = t * 16;
    int loc[16]; int s = 0;
    #pragma unroll
    for (int i = 0; i < 16; ++i) { loc[i] = s; s += deg[base + i]; }
    part[t] = s;
    __syncthreads();
    int sum = 0;
    for (int i = 0; i < t; ++i) sum += part[i];
    #pragma unroll
    for (int i = 0; i < 16; ++i) off[base + i] = sum + loc[i];
    if (t == 255) off[NN] = sum + s;
}

// scatter kept edges: csr[off[s] + cursor[s]++] = pos[dst]
__global__ void k_scatter(const int* __restrict__ g, int E, const int* __restrict__ keep,
                          const int* __restrict__ pos, const int* __restrict__ off,
                          int* __restrict__ cursor, int* __restrict__ csr) {
    int e = blockIdx.x * 256 + threadIdx.x;
    if (e >= E) return;
    int dd = g[E + e];
    if (!keep[dd]) return;
    int s = g[e];
    int p = atomicAdd(&cursor[s], 1);
    csr[off[s] + p] = pos[dd];
}

// reach2[i] = union over out-neighbors m of rowbits[m]; project to kept cols.
__global__ void k_sub(const u64* __restrict__ rowbits, const int* __restrict__ idxl,
                      u64* __restrict__ subbits, float* __restrict__ invdeg) {
    int wave = threadIdx.x >> 6, lane = threadIdx.x & 63;
    int r = blockIdx.x * 4 + wave;
    if (r >= KKEEP) return;
    int i = idxl[r];
    u64 rw = rowbits[(size_t)i * 64 + lane];
    u64 acc = 0;
    for (int wm = 0; wm < 64; ++wm) {
        u64 w = __shfl(rw, wm);
        while (w) {
            int b = __builtin_ctzll(w);
            w &= w - 1;
            int m = wm * 64 + b;
            acc |= rowbits[(size_t)m * 64 + lane];
        }
    }
    int cnt = 0;
    for (int wj = 0; wj < SUBW; ++wj) {
        int c = wj * 64 + lane;
        int ci = (c < KKEEP) ? idxl[c] : 0;
        u64 w = __shfl(acc, ci >> 6);
        int bit = (c < KKEEP) ? (int)((w >> (ci & 63)) & 1ull) : 0;
        u64 word = __ballot(bit);
        cnt += __popcll(word);
        if (lane == 0) subbits[(size_t)r * SUBW + wj] = word;
    }
    if (lane == 0) invdeg[r] = 1.0f / (float)cnt;
}

// Expand subbits -> dense bf16 binary matrix S [MP][KP] (1.0 or 0.0).
__global__ void k_expand(const u64* __restrict__ subbits, short* __restrict__ S) {
    int r = blockIdx.x;
    int t = threadIdx.x;
    u64* Srow = (u64*)(S + (size_t)r * KP);
    bool live = (r < KKEEP);
    #pragma unroll
    for (int i = 0; i < 2; ++i) {
        int q = t + i * 320;              // quad of 4 bf16 = 8 bytes
        if (q >= KP / 4) break;
        u64 outw = 0;
        if (live) {
            int c0 = q * 4;
            u64 w = subbits[(size_t)r * SUBW + (c0 >> 6)];
            int sh = c0 & 63;
            if ((w >> sh) & 1)       outw |= 0x3F80ull;
            if ((w >> (sh + 1)) & 1) outw |= 0x3F80ull << 16;
            if ((w >> (sh + 2)) & 1) outw |= 0x3F80ull << 32;
            if ((w >> (sh + 3)) & 1) outw |= 0x3F80ull << 48;
        }
        Srow[q] = outw;
    }
}

// t'[c] = (h0[idx[c]] * scores[idx[c]]) @ Wb * invdeg[c], stored transposed bf16.
__global__ void k_t(const float* __restrict__ h0, const float* __restrict__ scores,
                    const int* __restrict__ idxl, const float* __restrict__ Wb,
                    const float* __restrict__ invdeg, ushort_t* __restrict__ tT) {
    __shared__ float row[DD];
    int r = blockIdx.x, d = threadIdx.x;
    int i = idxl[r];
    row[d] = h0[(size_t)i * DD + d] * scores[i];
    __syncthreads();
    float acc = 0.f;
    #pragma unroll 4
    for (int k = 0; k < DD; ++k) acc += row[k] * Wb[k * DD + d];
    float v = acc * invdeg[r];
    __hip_bfloat16 b = __float2bfloat16(v);
    tT[(size_t)d * KP + r] = *reinterpret_cast<ushort_t*>(&b);
}

// hb = S @ t' via 16x16x32 bf16 MFMA, split-K=4 with f32 atomics.
__global__ void k_gemm(const short* __restrict__ S, const short* __restrict__ tT,
                       float* __restrict__ hb) {
    int wid = blockIdx.x * 4 + (threadIdx.x >> 6);
    int lane = threadIdx.x & 63;
    int tile = wid % (MT * NT);
    int sk = wid / (MT * NT);
    int rt = tile >> 3, ct = tile & 7;
    const short* arow = S + (size_t)(rt * 16 + (lane & 15)) * KP + ((lane >> 4) * 8) + sk * KCHUNK;
    const short* brow = tT + (size_t)(ct * 16 + (lane & 15)) * KP + ((lane >> 4) * 8) + sk * KCHUNK;
    f32x4 acc = {0.f, 0.f, 0.f, 0.f};
    #pragma unroll 4
    for (int kk = 0; kk < KCHUNK; kk += 32) {
        bf16x8 a = *(const bf16x8*)(arow + kk);
        bf16x8 b = *(const bf16x8*)(brow + kk);
        acc = __builtin_amdgcn_mfma_f32_16x16x32_bf16(a, b, acc, 0, 0, 0);
    }
    int col = ct * 16 + (lane & 15);
    int row0 = rt * 16 + ((lane >> 4) * 4);
    #pragma unroll
    for (int j = 0; j < 4; ++j) {
        int row = row0 + j;
        if (row < KKEEP) atomicAdd(&hb[(size_t)row * DD + col], acc[j]);
    }
}

// uu[r] = (hb[r] + bb) @ Wu
__global__ void k_u(const float* __restrict__ hb, const float* __restrict__ bb,
                    const float* __restrict__ Wu, float* __restrict__ uu) {
    __shared__ float row[DD];
    int r = blockIdx.x, d = threadIdx.x;
    row[d] = hb[(size_t)r * DD + d] + bb[d];
    __syncthreads();
    float acc = 0.f;
    #pragma unroll 4
    for (int k = 0; k < DD; ++k) acc += row[k] * Wu[k * DD + d];
    uu[(size_t)r * DD + d] = acc;
}

// out rows: hup[s] = sum over CSR of uu rows; out1 = hup+bu+h0; out2 = out1+h
__global__ void k_agg(const int* __restrict__ off, const int* __restrict__ csr,
                      const float* __restrict__ uu, const float* __restrict__ bu,
                      const float* __restrict__ h0, const float* __restrict__ h,
                      float* __restrict__ out) {
    int s = blockIdx.x, d = threadIdx.x;
    int b = off[s], e2 = off[s + 1];
    float acc = 0.f;
    for (int k = b; k < e2; ++k)
        acc += uu[(size_t)csr[k] * DD + d];
    size_t o = (size_t)s * DD + d;
    float a = acc + bu[d] + h0[o];
    out[o] = a;
    out[(size_t)NN * DD + o] = a + h[o];
}

extern "C" void kernel_launch(void* const* d_in, const int* in_sizes, int n_in,
                              void* d_out, int out_size, void* d_ws, size_t ws_size,
                              hipStream_t stream) {
    const int*   g  = (const int*)d_in[0];
    const float* h  = (const float*)d_in[1];
    const float* Wd = (const float*)d_in[2];
    const float* bd = (const float*)d_in[3];
    const float* pw = (const float*)d_in[4];
    const float* pb = (const float*)d_in[5];
    const float* Wb = (const float*)d_in[6];
    const float* bb = (const float*)d_in[7];
    const float* Wu = (const float*)d_in[8];
    const float* bu = (const float*)d_in[9];
    float* out = (float*)d_out;
    const int E = in_sizes[0] / 2;

    char* ws = (char*)d_ws;
    // S occupies [0, ~12.6MB); rowbits [0,2MB) dies before k_expand writes S;
    // uu reuses [0,1.3MB) after k_gemm has consumed S.
    short*    S       = (short*)(ws + 0);
    u64*      rowbits = (u64*)  (ws + 0);
    float*    uu      = (float*)(ws + 0);
    u64*      subbits = (u64*)  (ws + (13u << 20));   // 786 KB
    float*    h0      = (float*)(ws + (14u << 20));   // 2 MB
    ushort_t* tT      = (ushort_t*)(ws + (18u << 20));// 656 KB
    float*    hb      = (float*)(ws + (19u << 20));   // 1.26 MB
    int*      csr     = (int*)  (ws + 21180928u);     // 512 KB (kept edges)
    float*    scores  = (float*)(ws + (21u << 20));
    float*    invdeg  = (float*)(ws + (21u << 20) + 16384);
    int*      pos     = (int*)  (ws + (21u << 20) + 32768);
    int*      keep    = (int*)  (ws + (21u << 20) + 49152);
    int*      idxl    = (int*)  (ws + (21u << 20) + 65536);
    int*      deg     = (int*)  (ws + (21u << 20) + 81920);
    int*      cursor  = (int*)  (ws + (21u << 20) + 98304);
    int*      off     = (int*)  (ws + (21u << 20) + 114688); // NN+1 ints

    (void)hipMemsetAsync(rowbits, 0, (2u << 20), stream);
    (void)hipMemsetAsync(tT, 0, (size_t)DD * KP * sizeof(ushort_t), stream);
    (void)hipMemsetAsync(hb, 0, (size_t)KKEEP * DD * sizeof(float), stream);
    (void)hipMemsetAsync(deg, 0, 2 * 16384, stream);   // deg + cursor contiguous

    k_build_bits<<<(E + 255) / 256, 256, 0, stream>>>(g, E, rowbits);
    k_h0<<<NN, DD, 0, stream>>>(h, Wd, bd, h0);
    k_score<<<NN, DD, 0, stream>>>(h0, pw, pb, scores);
    k_rank<<<NN / 4, 256, 0, stream>>>(scores, keep, pos, idxl);
    k_deg<<<(E + 255) / 256, 256, 0, stream>>>(g, E, keep, deg);
    k_scan<<<1, 256, 0, stream>>>(deg, off);
    k_scatter<<<(E + 255) / 256, 256, 0, stream>>>(g, E, keep, pos, off, cursor, csr);
    k_sub<<<(KKEEP + 3) / 4, 256, 0, stream>>>(rowbits, idxl, subbits, invdeg);
    k_expand<<<MP, 320, 0, stream>>>(subbits, S);
    k_t<<<KKEEP, DD, 0, stream>>>(h0, scores, idxl, Wb, invdeg, tT);
    k_gemm<<<(MT * NT * SPLITK) / 4, 256, 0, stream>>>(S, (const short*)tT, hb);
    k_u<<<KKEEP, DD, 0, stream>>>(hb, bb, Wu, uu);
    k_agg<<<NN, DD, 0, stream>>>(off, csr, uu, bu, h0, h, out);
}